// Round 1
// baseline (559.335 us; speedup 1.0000x reference)
//
#include <hip/hip_runtime.h>

#define BB 32
#define TT 1600
#define EE 1024
#define DD 1024
#define AA 512
#define CC 10
#define KW 201

typedef __attribute__((ext_vector_type(8))) short short8;
typedef __attribute__((ext_vector_type(4))) float f32x4;

__device__ __forceinline__ unsigned short f2bf(float f) {
    unsigned int u = __float_as_uint(f);
    unsigned int r = (u + 0x7fffu + ((u >> 16) & 1u)) >> 16;  // RNE
    return (unsigned short)r;
}
__device__ __forceinline__ float sigm(float x) { return 1.f / (1.f + expf(-x)); }

// ---------------- ws layout (float units) ----------------
#define AF_OFF    0          // att_feat: 32*10 = 320
#define GATES_OFF 320        // gates: 32*2048 = 65536
#define DEC_OFF   65856      // dec_proj: 32*512 = 16384
#define R_OFF     82240      // r = h_new + dec_proj: 16384
#define E_OFF     98624      // e scores: 32*1600 = 51200
#define WBF_OFF   149824     // W_enc bf16: 524288 shorts = 262144 floats
// total: 411968 floats = ~1.65 MB

// ---------------- out layout (float units) ----------------
#define CTX_OFF 0        // 32*1024 = 32768
#define W_OFF   32768    // 32*1600 = 51200
#define H_OFF   83968    // 32*512
#define C_OFF   100352   // 32*512

// zero ctx region of d_out + att_feat in ws
__global__ void zero_kernel(float* out, float* af) {
    int i = blockIdx.x * 256 + threadIdx.x;
    if (i < 32768) out[CTX_OFF + i] = 0.f;
    else if (i < 32768 + 320) af[i - 32768] = 0.f;
}

// convert W_enc (512x1024 f32) -> bf16
__global__ void wconv_kernel(const float* __restrict__ W_enc, unsigned short* __restrict__ Wbf) {
    int i = blockIdx.x * 256 + threadIdx.x;   // float4 unit, 131072 total
    float4 v = reinterpret_cast<const float4*>(W_enc)[i];
    ushort4 p;
    p.x = f2bf(v.x); p.y = f2bf(v.y); p.z = f2bf(v.z); p.w = f2bf(v.w);
    reinterpret_cast<ushort4*>(Wbf)[i] = p;
}

// location conv (201 taps) + relu + global max pool -> att_feat[b][c]
// grid (B, C, 4), block 256; relu>=0 so atomicMax on uint bits is valid
__global__ void conv_kernel(const float* __restrict__ att_prev,
                            const float* __restrict__ conv_w,
                            unsigned int* __restrict__ af) {
    int b = blockIdx.x, c = blockIdx.y, seg = blockIdx.z;
    int ts = seg * 400;
    __shared__ float x[600];
    __shared__ float red[256];
    int tid = threadIdx.x;
    const float* xp = att_prev + b * TT;
    for (int i = tid; i < 600; i += 256) {
        int g = ts - 100 + i;
        x[i] = (g >= 0 && g < TT) ? xp[g] : 0.f;
    }
    __syncthreads();
    const float* wrow = conv_w + c * KW;   // uniform reads -> scalar loads
    float mx = 0.f;
    for (int tt = tid; tt < 400; tt += 256) {
        float s = 0.f;
        #pragma unroll 4
        for (int k = 0; k < KW; ++k) s += wrow[k] * x[tt + k];
        mx = fmaxf(mx, s);
    }
    red[tid] = mx; __syncthreads();
    for (int s = 128; s > 0; s >>= 1) {
        if (tid < s) red[tid] = fmaxf(red[tid], red[tid + s]);
        __syncthreads();
    }
    if (tid == 0) atomicMax(&af[b * CC + c], __float_as_uint(red[0]));
}

// gates[b][j] (j<2048) and dec_proj[b][a] (j-2048). grid 320, block 256 (8 j x 32 b)
__global__ void small_gemm_kernel(const float* __restrict__ af,
                                  const float* __restrict__ att_h,
                                  const float* __restrict__ dec_z,
                                  const float* __restrict__ W_ih,
                                  const float* __restrict__ W_hh,
                                  const float* __restrict__ W_dec,
                                  float* __restrict__ gates,
                                  float* __restrict__ dec_proj) {
    int tid = threadIdx.x;
    int b = tid & 31, jl = tid >> 5;
    int j = blockIdx.x * 8 + jl;
    if (j < 2048) {
        float s = 0.f;
        #pragma unroll
        for (int k = 0; k < 10; ++k) s += af[b * 10 + k] * W_ih[j * 10 + k];
        const float4* hh4 = reinterpret_cast<const float4*>(W_hh + (size_t)j * 512);
        const float4* h4  = reinterpret_cast<const float4*>(att_h + b * 512);
        #pragma unroll 4
        for (int k = 0; k < 128; ++k) {
            float4 a = h4[k], w = hh4[k];
            s += a.x * w.x + a.y * w.y + a.z * w.z + a.w * w.w;
        }
        gates[b * 2048 + j] = s;
    } else {
        int a = j - 2048;
        const float4* wd4 = reinterpret_cast<const float4*>(W_dec + (size_t)a * 1024);
        const float4* z4  = reinterpret_cast<const float4*>(dec_z + b * 1024);
        float s = 0.f;
        #pragma unroll 4
        for (int k = 0; k < 256; ++k) {
            float4 a4 = z4[k], w = wd4[k];
            s += a4.x * w.x + a4.y * w.y + a4.z * w.z + a4.w * w.w;
        }
        dec_proj[b * 512 + a] = s;
    }
}

// LSTM activations -> h_new, c_new (to d_out) and r = h_new + dec_proj (to ws)
__global__ void lstm_kernel(const float* __restrict__ gates,
                            const float* __restrict__ att_c,
                            const float* __restrict__ dec_proj,
                            float* __restrict__ out,
                            float* __restrict__ r) {
    int idx = blockIdx.x * 256 + threadIdx.x;   // 16384
    int b = idx >> 9, a = idx & 511;
    const float* g = gates + b * 2048;
    float ig = g[a], fg = g[512 + a], gg = g[1024 + a], og = g[1536 + a];
    float cn = sigm(fg) * att_c[idx] + sigm(ig) * tanhf(gg);
    float hn = sigm(og) * tanhf(cn);
    out[H_OFF + idx] = hn;
    out[C_OFF + idx] = cn;
    r[idx] = hn + dec_proj[idx];
}

// fused score GEMM: e[b,t] = sum_a W_g[a]*tanh(enc.W_enc^T + b_enc + r) + b_g
// block: 256 thr (4 waves), M=64 rows x N=512 (full A), K=1024 in 32-chunks
__global__ void __launch_bounds__(256, 2)
score_gemm_kernel(const float* __restrict__ enc,
                  const unsigned short* __restrict__ Wbf,
                  const float* __restrict__ b_enc,
                  const float* __restrict__ r_ws,
                  const float* __restrict__ W_g,
                  const float* __restrict__ b_g,
                  float* __restrict__ e_out) {
    __shared__ short As[64 * 40];    // 64 rows x 32 k, pad to 40
    __shared__ short Bs[512 * 40];   // 512 rows x 32 k, pad to 40
    __shared__ float e_sm[64];

    int tid = threadIdx.x;
    int lane = tid & 63, wv = tid >> 6;
    int col = lane & 15, quad = lane >> 4;
    int m0 = blockIdx.x * 64;
    int b = blockIdx.x / 25;   // T=1600 = 25*64, tiles never straddle b

    if (tid < 64) e_sm[tid] = 0.f;

    f32x4 acc[4][8];
    #pragma unroll
    for (int mt = 0; mt < 4; ++mt)
        #pragma unroll
        for (int nt = 0; nt < 8; ++nt)
            acc[mt][nt] = (f32x4){0.f, 0.f, 0.f, 0.f};

    for (int k0 = 0; k0 < 1024; k0 += 32) {
        __syncthreads();
        // stage A: 64x32 f32 -> bf16 LDS
        #pragma unroll
        for (int s = 0; s < 2; ++s) {
            int i = tid + s * 256;          // [0,512) float4 units
            int row = i >> 3, kq = i & 7;
            float4 v = *reinterpret_cast<const float4*>(
                enc + (size_t)(m0 + row) * 1024 + k0 + kq * 4);
            ushort4 p;
            p.x = f2bf(v.x); p.y = f2bf(v.y); p.z = f2bf(v.z); p.w = f2bf(v.w);
            *reinterpret_cast<ushort4*>(&As[row * 40 + kq * 4]) = p;
        }
        // stage B: 512x32 bf16 (pre-converted)
        #pragma unroll
        for (int s = 0; s < 8; ++s) {
            int i = tid + s * 256;          // [0,2048) 16B units
            int row = i >> 2, ko = (i & 3) * 8;
            int4 v = *reinterpret_cast<const int4*>(Wbf + (size_t)row * 1024 + k0 + ko);
            *reinterpret_cast<int4*>(&Bs[row * 40 + ko]) = v;
        }
        __syncthreads();

        short8 a_frag[4];
        #pragma unroll
        for (int mt = 0; mt < 4; ++mt)
            a_frag[mt] = *reinterpret_cast<const short8*>(&As[(mt * 16 + col) * 40 + quad * 8]);
        #pragma unroll
        for (int nt = 0; nt < 8; ++nt) {
            short8 b_frag = *reinterpret_cast<const short8*>(
                &Bs[(wv * 128 + nt * 16 + col) * 40 + quad * 8]);
            #pragma unroll
            for (int mt = 0; mt < 4; ++mt)
                acc[mt][nt] = __builtin_amdgcn_mfma_f32_16x16x32_bf16(
                    a_frag[mt], b_frag, acc[mt][nt], 0, 0, 0);
        }
    }

    // epilogue: tanh + W_g dot, reduce over n
    float bn[8], rn[8], wg[8];
    #pragma unroll
    for (int nt = 0; nt < 8; ++nt) {
        int n = wv * 128 + nt * 16 + col;
        bn[nt] = b_enc[n];
        rn[nt] = r_ws[b * 512 + n];
        wg[nt] = W_g[n];
    }
    #pragma unroll
    for (int mt = 0; mt < 4; ++mt) {
        #pragma unroll
        for (int reg = 0; reg < 4; ++reg) {
            float p = 0.f;
            #pragma unroll
            for (int nt = 0; nt < 8; ++nt)
                p += wg[nt] * tanhf(acc[mt][nt][reg] + bn[nt] + rn[nt]);
            p += __shfl_xor(p, 1);
            p += __shfl_xor(p, 2);
            p += __shfl_xor(p, 4);
            p += __shfl_xor(p, 8);
            if (col == 0) atomicAdd(&e_sm[mt * 16 + quad * 4 + reg], p);
        }
    }
    __syncthreads();
    if (tid < 64) e_out[m0 + tid] = e_sm[tid] + b_g[0];
}

// masked softmax over T with scaling 2.0; one block per b
__global__ void softmax_kernel(const float* __restrict__ e_ws,
                               const int* __restrict__ lens,
                               float* __restrict__ w_out) {
    int b = blockIdx.x, tid = threadIdx.x;
    int len = lens[b];
    const float* e = e_ws + b * TT;
    __shared__ float red[256];
    float mx = -3.4e38f;
    for (int t = tid; t < len; t += 256) mx = fmaxf(mx, e[t]);
    red[tid] = mx; __syncthreads();
    for (int s = 128; s > 0; s >>= 1) {
        if (tid < s) red[tid] = fmaxf(red[tid], red[tid + s]);
        __syncthreads();
    }
    mx = red[0]; __syncthreads();
    float sum = 0.f;
    for (int t = tid; t < len; t += 256) sum += expf(2.f * (e[t] - mx));
    red[tid] = sum; __syncthreads();
    for (int s = 128; s > 0; s >>= 1) {
        if (tid < s) red[tid] += red[tid + s];
        __syncthreads();
    }
    float inv = 1.f / red[0];
    for (int t = tid; t < TT; t += 256)
        w_out[b * TT + t] = (t < len) ? expf(2.f * (e[t] - mx)) * inv : 0.f;
}

// ctx[b,:] = sum_t w[b,t]*enc[b,t,:]; grid (B, 8), block 256 (thread owns float4)
__global__ void ctx_kernel(const float* __restrict__ enc,
                           const float* __restrict__ w,
                           float* __restrict__ ctx) {
    int b = blockIdx.x, seg = blockIdx.y;
    int t0 = seg * 200;
    const float* wrow = w + b * TT;
    float4 acc = {0.f, 0.f, 0.f, 0.f};
    for (int t = t0; t < t0 + 200; ++t) {
        float wv = wrow[t];
        if (wv == 0.f) continue;   // masked frames: skip the load entirely
        float4 v = *reinterpret_cast<const float4*>(
            enc + (size_t)(b * TT + t) * 1024 + threadIdx.x * 4);
        acc.x += wv * v.x; acc.y += wv * v.y; acc.z += wv * v.z; acc.w += wv * v.w;
    }
    float* dst = ctx + b * 1024 + threadIdx.x * 4;
    atomicAdd(dst + 0, acc.x);
    atomicAdd(dst + 1, acc.y);
    atomicAdd(dst + 2, acc.z);
    atomicAdd(dst + 3, acc.w);
}

extern "C" void kernel_launch(void* const* d_in, const int* in_sizes, int n_in,
                              void* d_out, int out_size, void* d_ws, size_t ws_size,
                              hipStream_t stream) {
    const float* enc      = (const float*)d_in[0];
    const int*   lens     = (const int*)d_in[1];
    const float* dec_z    = (const float*)d_in[2];
    const float* att_prev = (const float*)d_in[3];
    const float* att_h    = (const float*)d_in[4];
    const float* att_c    = (const float*)d_in[5];
    const float* W_enc    = (const float*)d_in[6];
    const float* b_enc    = (const float*)d_in[7];
    const float* W_dec    = (const float*)d_in[8];
    const float* conv_w   = (const float*)d_in[9];
    const float* W_ih     = (const float*)d_in[10];
    const float* W_hh     = (const float*)d_in[11];
    const float* W_g      = (const float*)d_in[12];
    const float* b_g      = (const float*)d_in[13];

    float* out = (float*)d_out;
    float* ws  = (float*)d_ws;
    float* af        = ws + AF_OFF;
    float* gates     = ws + GATES_OFF;
    float* dec_proj  = ws + DEC_OFF;
    float* r_ws      = ws + R_OFF;
    float* e_ws      = ws + E_OFF;
    unsigned short* Wbf = (unsigned short*)(ws + WBF_OFF);

    zero_kernel<<<130, 256, 0, stream>>>(out, af);
    wconv_kernel<<<512, 256, 0, stream>>>(W_enc, Wbf);
    conv_kernel<<<dim3(BB, CC, 4), 256, 0, stream>>>(att_prev, conv_w, (unsigned int*)af);
    small_gemm_kernel<<<320, 256, 0, stream>>>(af, att_h, dec_z, W_ih, W_hh, W_dec,
                                               gates, dec_proj);
    lstm_kernel<<<64, 256, 0, stream>>>(gates, att_c, dec_proj, out, r_ws);
    score_gemm_kernel<<<800, 256, 0, stream>>>(enc, Wbf, b_enc, r_ws, W_g, b_g, e_ws);
    softmax_kernel<<<BB, 256, 0, stream>>>(e_ws, lens, out + W_OFF);
    ctx_kernel<<<dim3(BB, 8), 256, 0, stream>>>(enc, out + W_OFF, out + CTX_OFF);
}

// Round 2
// 524.829 us; speedup vs baseline: 1.0657x; 1.0657x over previous
//
#include <hip/hip_runtime.h>
#include <hip/hip_bf16.h>

#define BB 32
#define TT 1600
#define EE 1024
#define AA 512
#define CC 10
#define KW 201

typedef __attribute__((ext_vector_type(8))) short short8;
typedef __attribute__((ext_vector_type(4))) float f32x4;

__device__ __forceinline__ float sigm(float x) { return 1.f / (1.f + expf(-x)); }

// pack 2 floats -> 2 bf16 (RNE) in one uint; lowers to v_cvt_pk_bf16_f32 on gfx950
__device__ __forceinline__ unsigned int cvt2(float a, float b) {
    float2 f2; f2.x = a; f2.y = b;
    __hip_bfloat162 h = __float22bfloat162_rn(f2);
    unsigned int r;
    __builtin_memcpy(&r, &h, 4);
    return r;
}

// async global->LDS, 16 bytes per lane (global_load_lds_dwordx4)
__device__ __forceinline__ void gl_lds16(const void* g, void* l) {
    __builtin_amdgcn_global_load_lds(
        (const __attribute__((address_space(1))) unsigned int*)g,
        (__attribute__((address_space(3))) unsigned int*)l, 16, 0, 0);
}

// ---------------- ws layout (float units) ----------------
#define AF_OFF    0          // att_feat: 32*10 = 320
#define GATES_OFF 320        // gates: 32*2048 = 65536
#define DEC_OFF   65856      // dec_proj: 32*512 = 16384
#define R_OFF     82240      // r = h_new + dec_proj: 16384
#define E_OFF     98624      // e partial sums: 32*1600 = 51200
#define WBF_OFF   149824     // W_enc bf16: 524288 shorts = 262144 floats
// total ~412K floats = 1.65 MB

// ---------------- out layout (float units) ----------------
#define CTX_OFF 0        // 32*1024
#define W_OFF   32768    // 32*1600
#define H_OFF   83968    // 32*512
#define C_OFF   100352   // 32*512

// zero: ctx (32768) + af (320) + e_ws (51200)
__global__ void zero_kernel(float* out, float* af, float* e_ws) {
    int i = blockIdx.x * 256 + threadIdx.x;
    if (i < 32768) out[CTX_OFF + i] = 0.f;
    else if (i < 33088) af[i - 32768] = 0.f;
    else if (i < 84288) e_ws[i - 33088] = 0.f;
}

// W_enc (512x1024 f32) -> bf16
__global__ void wconv_kernel(const float* __restrict__ W_enc, unsigned short* __restrict__ Wbf) {
    int i = blockIdx.x * 256 + threadIdx.x;   // float4 unit, 131072 total
    float4 v = reinterpret_cast<const float4*>(W_enc)[i];
    uint2 p;
    p.x = cvt2(v.x, v.y);
    p.y = cvt2(v.z, v.w);
    reinterpret_cast<uint2*>(Wbf)[i] = p;
}

// location conv (201 taps) + relu + global max pool -> att_feat[b][c]
__global__ void conv_kernel(const float* __restrict__ att_prev,
                            const float* __restrict__ conv_w,
                            unsigned int* __restrict__ af) {
    int b = blockIdx.x, c = blockIdx.y, seg = blockIdx.z;
    int ts = seg * 400;
    __shared__ float x[600];
    __shared__ float wsm[KW];
    __shared__ float red[256];
    int tid = threadIdx.x;
    const float* xp = att_prev + b * TT;
    for (int i = tid; i < 600; i += 256) {
        int g = ts - 100 + i;
        x[i] = (g >= 0 && g < TT) ? xp[g] : 0.f;
    }
    if (tid < KW) wsm[tid] = conv_w[c * KW + tid];
    __syncthreads();
    float mx = 0.f;
    for (int tt = tid; tt < 400; tt += 256) {
        float s = 0.f;
        #pragma unroll 4
        for (int k = 0; k < KW; ++k) s += wsm[k] * x[tt + k];
        mx = fmaxf(mx, s);
    }
    red[tid] = mx; __syncthreads();
    for (int s = 128; s > 0; s >>= 1) {
        if (tid < s) red[tid] = fmaxf(red[tid], red[tid + s]);
        __syncthreads();
    }
    if (tid == 0) atomicMax(&af[b * CC + c], __float_as_uint(red[0]));
}

// gates[b][j] (j<2048) and dec_proj[b][a] (j-2048)
__global__ void small_gemm_kernel(const float* __restrict__ af,
                                  const float* __restrict__ att_h,
                                  const float* __restrict__ dec_z,
                                  const float* __restrict__ W_ih,
                                  const float* __restrict__ W_hh,
                                  const float* __restrict__ W_dec,
                                  float* __restrict__ gates,
                                  float* __restrict__ dec_proj) {
    int tid = threadIdx.x;
    int b = tid & 31, jl = tid >> 5;
    int j = blockIdx.x * 8 + jl;
    if (j < 2048) {
        float s = 0.f;
        #pragma unroll
        for (int k = 0; k < 10; ++k) s += af[b * 10 + k] * W_ih[j * 10 + k];
        const float4* hh4 = reinterpret_cast<const float4*>(W_hh + (size_t)j * 512);
        const float4* h4  = reinterpret_cast<const float4*>(att_h + b * 512);
        #pragma unroll 4
        for (int k = 0; k < 128; ++k) {
            float4 a = h4[k], w = hh4[k];
            s += a.x * w.x + a.y * w.y + a.z * w.z + a.w * w.w;
        }
        gates[b * 2048 + j] = s;
    } else {
        int a = j - 2048;
        const float4* wd4 = reinterpret_cast<const float4*>(W_dec + (size_t)a * 1024);
        const float4* z4  = reinterpret_cast<const float4*>(dec_z + b * 1024);
        float s = 0.f;
        #pragma unroll 4
        for (int k = 0; k < 256; ++k) {
            float4 a4 = z4[k], w = wd4[k];
            s += a4.x * w.x + a4.y * w.y + a4.z * w.z + a4.w * w.w;
        }
        dec_proj[b * 512 + a] = s;
    }
}

// LSTM activations -> h_new, c_new (d_out) and r = h_new + dec_proj (ws)
__global__ void lstm_kernel(const float* __restrict__ gates,
                            const float* __restrict__ att_c,
                            const float* __restrict__ dec_proj,
                            float* __restrict__ out,
                            float* __restrict__ r) {
    int idx = blockIdx.x * 256 + threadIdx.x;   // 16384
    int b = idx >> 9, a = idx & 511;
    const float* g = gates + b * 2048;
    float ig = g[a], fg = g[512 + a], gg = g[1024 + a], og = g[1536 + a];
    float cn = sigm(fg) * att_c[idx] + sigm(ig) * tanhf(gg);
    float hn = sigm(og) * tanhf(cn);
    out[H_OFF + idx] = hn;
    out[C_OFF + idx] = cn;
    r[idx] = hn + dec_proj[idx];
}

// fused score GEMM, m97 structure: 128(M) x 128(N) tile, BK=32, K=1024.
// grid (4 N-cols, 400 M-rows) so N-siblings co-reside for A L2 reuse.
// epilogue: partial e[m] = sum_n wg[n]*tanh(acc + b_enc[n] + r[b][n]) -> atomicAdd
__global__ void __launch_bounds__(256, 2)
score_gemm_kernel(const float* __restrict__ enc,
                  const unsigned short* __restrict__ Wbf,
                  const float* __restrict__ b_enc,
                  const float* __restrict__ r_ws,
                  const float* __restrict__ W_g,
                  float* __restrict__ e_ws) {
    __shared__ __align__(16) short As[128 * 32];   // 8 KB bf16
    __shared__ __align__(16) short Bs[128 * 32];   // 8 KB bf16

    int tid = threadIdx.x;
    int lane = tid & 63, wv = tid >> 6;
    int col = lane & 15, quad = lane >> 4;
    int wm = wv >> 1, wn = wv & 1;
    int n0 = blockIdx.x * 128;
    int m0 = blockIdx.y * 128;

    // A staging: thread owns 16 floats of row arow, half ahalf
    int arow = tid >> 1, ahalf = (tid & 1) * 16;
    const float* abase = enc + (size_t)(m0 + arow) * EE + ahalf;

    f32x4 acc[4][4];
    #pragma unroll
    for (int mt = 0; mt < 4; ++mt)
        #pragma unroll
        for (int nt = 0; nt < 4; ++nt)
            acc[mt][nt] = (f32x4){0.f, 0.f, 0.f, 0.f};

    for (int k0 = 0; k0 < EE; k0 += 32) {
        // A global prefetch (overlaps other waves' MFMA)
        const float4* ag = reinterpret_cast<const float4*>(abase + k0);
        float4 v0 = ag[0], v1 = ag[1], v2 = ag[2], v3 = ag[3];

        __syncthreads();   // previous tile fully consumed

        // B: async global->LDS, 2x16B per thread, lane-contiguous layout
        {
            int c = tid;
            gl_lds16(Wbf + (size_t)(n0 + (c >> 2)) * EE + k0 + (c & 3) * 8, Bs + c * 8);
            c = tid + 256;
            gl_lds16(Wbf + (size_t)(n0 + (c >> 2)) * EE + k0 + (c & 3) * 8, Bs + c * 8);
        }
        // A: convert f32 -> bf16, write 2x16B
        int4 st0, st1;
        st0.x = cvt2(v0.x, v0.y); st0.y = cvt2(v0.z, v0.w);
        st0.z = cvt2(v1.x, v1.y); st0.w = cvt2(v1.z, v1.w);
        st1.x = cvt2(v2.x, v2.y); st1.y = cvt2(v2.z, v2.w);
        st1.z = cvt2(v3.x, v3.y); st1.w = cvt2(v3.z, v3.w);
        *reinterpret_cast<int4*>(&As[arow * 32 + ahalf]) = st0;
        *reinterpret_cast<int4*>(&As[arow * 32 + ahalf + 8]) = st1;

        __syncthreads();   // barrier drains vmcnt (global_load_lds) + lgkmcnt

        short8 a_frag[4];
        #pragma unroll
        for (int mt = 0; mt < 4; ++mt)
            a_frag[mt] = *reinterpret_cast<const short8*>(
                &As[(wm * 64 + mt * 16 + col) * 32 + quad * 8]);
        #pragma unroll
        for (int nt = 0; nt < 4; ++nt) {
            short8 b_frag = *reinterpret_cast<const short8*>(
                &Bs[(wn * 64 + nt * 16 + col) * 32 + quad * 8]);
            #pragma unroll
            for (int mt = 0; mt < 4; ++mt)
                acc[mt][nt] = __builtin_amdgcn_mfma_f32_16x16x32_bf16(
                    a_frag[mt], b_frag, acc[mt][nt], 0, 0, 0);
        }
    }

    // epilogue
    int n_base = n0 + wn * 64;
    float wg[4], bn[4];
    #pragma unroll
    for (int nt = 0; nt < 4; ++nt) {
        int n = n_base + nt * 16 + col;
        wg[nt] = W_g[n];
        bn[nt] = b_enc[n];
    }
    #pragma unroll
    for (int mt = 0; mt < 4; ++mt) {
        int mg = m0 + wm * 64 + mt * 16;      // 16-row group never straddles a batch row
        int bb = mg / TT;
        float rn[4];
        #pragma unroll
        for (int nt = 0; nt < 4; ++nt)
            rn[nt] = r_ws[bb * AA + n_base + nt * 16 + col];
        #pragma unroll
        for (int reg = 0; reg < 4; ++reg) {
            float p = 0.f;
            #pragma unroll
            for (int nt = 0; nt < 4; ++nt)
                p += wg[nt] * tanhf(acc[mt][nt][reg] + bn[nt] + rn[nt]);
            p += __shfl_xor(p, 1);
            p += __shfl_xor(p, 2);
            p += __shfl_xor(p, 4);
            p += __shfl_xor(p, 8);
            if (col == 0) atomicAdd(&e_ws[mg + quad * 4 + reg], p);
        }
    }
}

// masked softmax over T with scaling 2.0 (b_g omitted: softmax shift-invariant)
__global__ void softmax_kernel(const float* __restrict__ e_ws,
                               const int* __restrict__ lens,
                               float* __restrict__ w_out) {
    int b = blockIdx.x, tid = threadIdx.x;
    int len = lens[b];
    const float* e = e_ws + b * TT;
    __shared__ float red[256];
    float mx = -3.4e38f;
    for (int t = tid; t < len; t += 256) mx = fmaxf(mx, e[t]);
    red[tid] = mx; __syncthreads();
    for (int s = 128; s > 0; s >>= 1) {
        if (tid < s) red[tid] = fmaxf(red[tid], red[tid + s]);
        __syncthreads();
    }
    mx = red[0]; __syncthreads();
    float sum = 0.f;
    for (int t = tid; t < len; t += 256) sum += expf(2.f * (e[t] - mx));
    red[tid] = sum; __syncthreads();
    for (int s = 128; s > 0; s >>= 1) {
        if (tid < s) red[tid] += red[tid + s];
        __syncthreads();
    }
    float inv = 1.f / red[0];
    for (int t = tid; t < TT; t += 256)
        w_out[b * TT + t] = (t < len) ? expf(2.f * (e[t] - mx)) * inv : 0.f;
}

// ctx[b,:] += sum_t w[b,t]*enc[b,t,:]; branch-free (masked w == 0), unroll 4
__global__ void ctx_kernel(const float* __restrict__ enc,
                           const float* __restrict__ w,
                           float* __restrict__ ctx) {
    int b = blockIdx.x, seg = blockIdx.y;
    int t0 = seg * 100;
    const float* wrow = w + b * TT + t0;
    const float* base = enc + ((size_t)(b * TT + t0)) * EE + threadIdx.x * 4;
    float4 acc = {0.f, 0.f, 0.f, 0.f};
    #pragma unroll 1
    for (int i = 0; i < 100; i += 4) {
        float w0 = wrow[i], w1 = wrow[i + 1], w2 = wrow[i + 2], w3 = wrow[i + 3];
        float4 v0 = *reinterpret_cast<const float4*>(base + (size_t)(i + 0) * EE);
        float4 v1 = *reinterpret_cast<const float4*>(base + (size_t)(i + 1) * EE);
        float4 v2 = *reinterpret_cast<const float4*>(base + (size_t)(i + 2) * EE);
        float4 v3 = *reinterpret_cast<const float4*>(base + (size_t)(i + 3) * EE);
        acc.x += w0 * v0.x + w1 * v1.x + w2 * v2.x + w3 * v3.x;
        acc.y += w0 * v0.y + w1 * v1.y + w2 * v2.y + w3 * v3.y;
        acc.z += w0 * v0.z + w1 * v1.z + w2 * v2.z + w3 * v3.z;
        acc.w += w0 * v0.w + w1 * v1.w + w2 * v2.w + w3 * v3.w;
    }
    float* dst = ctx + b * EE + threadIdx.x * 4;
    atomicAdd(dst + 0, acc.x);
    atomicAdd(dst + 1, acc.y);
    atomicAdd(dst + 2, acc.z);
    atomicAdd(dst + 3, acc.w);
}

extern "C" void kernel_launch(void* const* d_in, const int* in_sizes, int n_in,
                              void* d_out, int out_size, void* d_ws, size_t ws_size,
                              hipStream_t stream) {
    const float* enc      = (const float*)d_in[0];
    const int*   lens     = (const int*)d_in[1];
    const float* dec_z    = (const float*)d_in[2];
    const float* att_prev = (const float*)d_in[3];
    const float* att_h    = (const float*)d_in[4];
    const float* att_c    = (const float*)d_in[5];
    const float* W_enc    = (const float*)d_in[6];
    const float* b_enc    = (const float*)d_in[7];
    const float* W_dec    = (const float*)d_in[8];
    const float* conv_w   = (const float*)d_in[9];
    const float* W_ih     = (const float*)d_in[10];
    const float* W_hh     = (const float*)d_in[11];
    const float* W_g      = (const float*)d_in[12];

    float* out = (float*)d_out;
    float* ws  = (float*)d_ws;
    float* af        = ws + AF_OFF;
    float* gates     = ws + GATES_OFF;
    float* dec_proj  = ws + DEC_OFF;
    float* r_ws      = ws + R_OFF;
    float* e_ws      = ws + E_OFF;
    unsigned short* Wbf = (unsigned short*)(ws + WBF_OFF);

    zero_kernel<<<330, 256, 0, stream>>>(out, af, e_ws);
    wconv_kernel<<<512, 256, 0, stream>>>(W_enc, Wbf);
    conv_kernel<<<dim3(BB, CC, 4), 256, 0, stream>>>(att_prev, conv_w, (unsigned int*)af);
    small_gemm_kernel<<<320, 256, 0, stream>>>(af, att_h, dec_z, W_ih, W_hh, W_dec,
                                               gates, dec_proj);
    lstm_kernel<<<64, 256, 0, stream>>>(gates, att_c, dec_proj, out, r_ws);
    score_gemm_kernel<<<dim3(4, 400), 256, 0, stream>>>(enc, Wbf, b_enc, r_ws, W_g, e_ws);
    softmax_kernel<<<BB, 256, 0, stream>>>(e_ws, lens, out + W_OFF);
    ctx_kernel<<<dim3(BB, 16), 256, 0, stream>>>(enc, out + W_OFF, out + CTX_OFF);
}

// Round 3
// 497.137 us; speedup vs baseline: 1.1251x; 1.0557x over previous
//
#include <hip/hip_runtime.h>
#include <hip/hip_bf16.h>

#define BB 32
#define TT 1600
#define EE 1024
#define AA 512
#define CC 10
#define KW 201

typedef __attribute__((ext_vector_type(8))) short short8;
typedef __attribute__((ext_vector_type(4))) float f32x4;

__device__ __forceinline__ float sigm(float x) { return 1.f / (1.f + expf(-x)); }

// pack 2 floats -> 2 bf16 (RNE): v_cvt_pk_bf16_f32
__device__ __forceinline__ unsigned int cvt2(float a, float b) {
    float2 f2; f2.x = a; f2.y = b;
    __hip_bfloat162 h = __float22bfloat162_rn(f2);
    unsigned int r;
    __builtin_memcpy(&r, &h, 4);
    return r;
}

// async global->LDS 16 B/lane (global_load_lds_dwordx4); dest must be lane-linear
__device__ __forceinline__ void gl_lds16(const void* g, void* l) {
    __builtin_amdgcn_global_load_lds(
        (const __attribute__((address_space(1))) unsigned int*)g,
        (__attribute__((address_space(3))) unsigned int*)l, 16, 0, 0);
}

// ---------------- ws layout (float units) ----------------
#define AF_OFF   0        // att_feat 32*10 = 320
#define R_OFF    320      // r = h_new + dec_proj: 16384
#define E_OFF    16704    // e scores: 51200
#define WBF_OFF  67904    // W_enc bf16: 524288 shorts = 262144 floats
// total ~330K floats = 1.29 MB

// ---------------- out layout (float units) ----------------
#define CTX_OFF 0
#define W_OFF   32768
#define H_OFF   83968
#define C_OFF   100352

// K1: blocks 0..319 = location conv (one block per (b,c), full T, no atomics);
//     blocks 320..831 = W_enc f32->bf16 conversion
__global__ void prep_kernel(const float* __restrict__ att_prev,
                            const float* __restrict__ conv_w,
                            const float* __restrict__ W_enc,
                            float* __restrict__ af,
                            unsigned short* __restrict__ Wbf) {
    int bx = blockIdx.x, tid = threadIdx.x;
    if (bx >= 320) {
        int i = (bx - 320) * 256 + tid;   // float4 unit, 131072 total
        float4 v = reinterpret_cast<const float4*>(W_enc)[i];
        uint2 p;
        p.x = cvt2(v.x, v.y);
        p.y = cvt2(v.z, v.w);
        reinterpret_cast<uint2*>(Wbf)[i] = p;
        return;
    }
    int b = bx / 10, c = bx % 10;
    __shared__ float xs[1808];     // t in [-100, 1707], padded
    __shared__ float wsm[KW];
    __shared__ float red[256];
    const float* xp = att_prev + b * TT;
    for (int i = tid; i < 1808; i += 256) {
        int g = i - 100;
        xs[i] = (g >= 0 && g < TT) ? xp[g] : 0.f;
    }
    if (tid < KW) wsm[tid] = conv_w[c * KW + tid];
    __syncthreads();
    float mx = 0.f;   // relu >= 0 so 0 is a valid identity
    #pragma unroll 1
    for (int sweep = 0; sweep < 2; ++sweep) {
        int t0 = sweep * 1024 + tid * 4;
        if (t0 >= TT) break;
        // rolling window: s_j = sum_k w[k]*xs[t0+j+k]
        float a0 = xs[t0], a1 = xs[t0 + 1], a2 = xs[t0 + 2], a3 = xs[t0 + 3];
        float s0 = 0.f, s1 = 0.f, s2 = 0.f, s3 = 0.f;
        #pragma unroll 4
        for (int k = 0; k < KW; ++k) {
            float w = wsm[k];
            s0 += w * a0; s1 += w * a1; s2 += w * a2; s3 += w * a3;
            a0 = a1; a1 = a2; a2 = a3;
            a3 = xs[t0 + k + 4];
        }
        mx = fmaxf(mx, fmaxf(fmaxf(s0, s1), fmaxf(s2, s3)));
    }
    red[tid] = mx; __syncthreads();
    for (int s = 128; s > 0; s >>= 1) {
        if (tid < s) red[tid] = fmaxf(red[tid], red[tid + s]);
        __syncthreads();
    }
    if (tid == 0) af[b * CC + c] = red[0];
}

// K2: gates + dec_proj + LSTM + r, one block per 2 a-values (grid 256, 512 thr).
// tid<256: gate dots (u = gate*2+ai); tid>=256: dec_proj quarter-dots; then LSTM.
__global__ void gates_lstm_kernel(const float* __restrict__ af,
                                  const float* __restrict__ att_h,
                                  const float* __restrict__ dec_z,
                                  const float* __restrict__ att_c,
                                  const float* __restrict__ W_ih,
                                  const float* __restrict__ W_hh,
                                  const float* __restrict__ W_dec,
                                  float* __restrict__ out,
                                  float* __restrict__ r_ws) {
    __shared__ float gsm[8][32];
    __shared__ float dsm[8][32];
    int tid = threadIdx.x;
    int a0 = blockIdx.x * 2;
    int b = tid & 31;
    if (tid < 256) {
        int u = tid >> 5;                 // 0..7 = gate*2 + ai
        int gate = u >> 1, ai = u & 1;
        int j = gate * 512 + a0 + ai;
        float s = 0.f;
        #pragma unroll
        for (int k = 0; k < 10; ++k) s += af[b * 10 + k] * W_ih[j * 10 + k];
        const float4* wr = reinterpret_cast<const float4*>(W_hh + (size_t)j * 512);
        const float4* hr = reinterpret_cast<const float4*>(att_h + b * 512);
        #pragma unroll 4
        for (int k = 0; k < 128; ++k) {
            float4 w = wr[k], h = hr[k];
            s += w.x * h.x + w.y * h.y + w.z * h.z + w.w * h.w;
        }
        gsm[u][b] = s;
    } else {
        int v = (tid - 256) >> 5;         // 0..7 = q*2 + ai
        int ai = v & 1, q = v >> 1;
        int a = a0 + ai;
        const float4* wr = reinterpret_cast<const float4*>(W_dec + (size_t)a * 1024) + q * 64;
        const float4* zr = reinterpret_cast<const float4*>(dec_z + (size_t)b * 1024) + q * 64;
        float s = 0.f;
        #pragma unroll 4
        for (int k = 0; k < 64; ++k) {
            float4 w = wr[k], z = zr[k];
            s += w.x * z.x + w.y * z.y + w.z * z.z + w.w * z.w;
        }
        dsm[v][b] = s;
    }
    __syncthreads();
    if (tid < 64) {
        int ai = tid >> 5;
        int a = a0 + ai;
        float ig = gsm[ai][b], fg = gsm[2 + ai][b], gg = gsm[4 + ai][b], og = gsm[6 + ai][b];
        float cn = sigm(fg) * att_c[b * 512 + a] + sigm(ig) * tanhf(gg);
        float hn = sigm(og) * tanhf(cn);
        out[H_OFF + b * 512 + a] = hn;
        out[C_OFF + b * 512 + a] = cn;
        float dec = dsm[ai][b] + dsm[2 + ai][b] + dsm[4 + ai][b] + dsm[6 + ai][b];
        r_ws[b * 512 + a] = hn + dec;
    }
}

// K3: fused score GEMM. Block = 128 M-rows x full N=512, K=1024 (BK=32).
// A read exactly once from HBM. 1024 thr = 16 waves (2m x 8n), wave tile 64x64.
// Per K-chunk, two N-half phases: compute half h from Bs[h] while global_load_lds
// fills the other; A prefetched one chunk ahead into VGPRs, cvt->LDS dbuf.
// LDS k-major slot layout: group g (16 rows), slot = quad*16 + row -> 2-way (free).
__global__ void __launch_bounds__(1024, 4)
score_gemm_kernel(const float* __restrict__ enc,
                  const unsigned short* __restrict__ Wbf,
                  const float* __restrict__ b_enc,
                  const float* __restrict__ r_ws,
                  const float* __restrict__ W_g,
                  float* __restrict__ e_ws) {
    __shared__ __align__(16) short As[2][4096];   // 128 x 32 bf16, dbuf
    __shared__ __align__(16) short Bs[2][8192];   // 256 x 32 bf16 per N-half
    __shared__ float e_part[8][128];

    int tid = threadIdx.x;
    int lane = tid & 63, wv = tid >> 6;
    int wm = wv >> 3, wn = wv & 7;
    int col = lane & 15, quad = lane >> 4;
    int m0 = blockIdx.x * 128;

    // B staging: thread -> one 16B slot per issue; slot s=tid: g=s>>6, kq=(s>>4)&3, nn=s&15
    const unsigned short* bsrc = Wbf + (size_t)((tid >> 6) * 16 + (tid & 15)) * EE
                                 + ((tid >> 4) & 3) * 8;
    // A staging: thread -> 4 floats; row=tid>>3, kq2=tid&7
    int arow = tid >> 3, akq2 = tid & 7;
    const float* asrc = enc + (size_t)(m0 + arow) * EE + akq2 * 4;
    int adst = (arow >> 4) * 512 + ((akq2 >> 1) * 16 + (arow & 15)) * 8 + (akq2 & 1) * 4;

    f32x4 acc[4][2][2];
    #pragma unroll
    for (int mt = 0; mt < 4; ++mt)
        #pragma unroll
        for (int h = 0; h < 2; ++h)
            #pragma unroll
            for (int nt = 0; nt < 2; ++nt)
                acc[mt][h][nt] = (f32x4){0.f, 0.f, 0.f, 0.f};

    // prologue: stage A(k=0) -> As[0], B(k=0, half0) -> Bs[0]
    {
        gl_lds16(bsrc, &Bs[0][tid * 8]);
        float4 v = *reinterpret_cast<const float4*>(asrc);
        uint2 p; p.x = cvt2(v.x, v.y); p.y = cvt2(v.z, v.w);
        *reinterpret_cast<uint2*>(&As[0][adst]) = p;
    }
    __syncthreads();

    int bufA = 0;
    for (int k0 = 0; k0 < EE; k0 += 32) {
        bool last = (k0 == EE - 32);
        // ---- phase 0: compute N-half 0, stage B(k0, half1) ----
        gl_lds16(bsrc + (size_t)256 * EE + k0, &Bs[1][tid * 8]);
        short8 a_frag[4];
        #pragma unroll
        for (int mt = 0; mt < 4; ++mt)
            a_frag[mt] = *reinterpret_cast<const short8*>(
                &As[bufA][(wm * 4 + mt) * 512 + (quad * 16 + col) * 8]);
        #pragma unroll
        for (int nt = 0; nt < 2; ++nt) {
            short8 bf = *reinterpret_cast<const short8*>(
                &Bs[0][(wn * 2 + nt) * 512 + (quad * 16 + col) * 8]);
            #pragma unroll
            for (int mt = 0; mt < 4; ++mt)
                acc[mt][0][nt] = __builtin_amdgcn_mfma_f32_16x16x32_bf16(
                    a_frag[mt], bf, acc[mt][0][nt], 0, 0, 0);
        }
        __syncthreads();
        // ---- phase 1: compute N-half 1, stage B(k0+32, half0) + A(k0+32) ----
        float4 av;
        if (!last) {
            av = *reinterpret_cast<const float4*>(asrc + k0 + 32);
            gl_lds16(bsrc + k0 + 32, &Bs[0][tid * 8]);
        }
        #pragma unroll
        for (int nt = 0; nt < 2; ++nt) {
            short8 bf = *reinterpret_cast<const short8*>(
                &Bs[1][(wn * 2 + nt) * 512 + (quad * 16 + col) * 8]);
            #pragma unroll
            for (int mt = 0; mt < 4; ++mt)
                acc[mt][1][nt] = __builtin_amdgcn_mfma_f32_16x16x32_bf16(
                    a_frag[mt], bf, acc[mt][1][nt], 0, 0, 0);
        }
        if (!last) {
            uint2 p; p.x = cvt2(av.x, av.y); p.y = cvt2(av.z, av.w);
            *reinterpret_cast<uint2*>(&As[bufA ^ 1][adst]) = p;
        }
        __syncthreads();
        bufA ^= 1;
    }

    // epilogue: e_row_partial = sum_n wg[n]*tanh(acc + b_enc[n] + r[b][n])
    float wg[2][2], bn[2][2];
    #pragma unroll
    for (int h = 0; h < 2; ++h)
        #pragma unroll
        for (int nt = 0; nt < 2; ++nt) {
            int n = h * 256 + wn * 32 + nt * 16 + col;
            wg[h][nt] = W_g[n];
            bn[h][nt] = b_enc[n];
        }
    #pragma unroll
    for (int mt = 0; mt < 4; ++mt) {
        int mg = m0 + wm * 64 + mt * 16;   // 16-row groups never straddle batch rows
        int bb = mg / TT;
        float rr[2][2];
        #pragma unroll
        for (int h = 0; h < 2; ++h)
            #pragma unroll
            for (int nt = 0; nt < 2; ++nt)
                rr[h][nt] = r_ws[bb * AA + h * 256 + wn * 32 + nt * 16 + col];
        #pragma unroll
        for (int reg = 0; reg < 4; ++reg) {
            float p = 0.f;
            #pragma unroll
            for (int h = 0; h < 2; ++h)
                #pragma unroll
                for (int nt = 0; nt < 2; ++nt)
                    p += wg[h][nt] * tanhf(acc[mt][h][nt][reg] + bn[h][nt] + rr[h][nt]);
            p += __shfl_xor(p, 1);
            p += __shfl_xor(p, 2);
            p += __shfl_xor(p, 4);
            p += __shfl_xor(p, 8);
            if (col == 0) e_part[wn][wm * 64 + mt * 16 + quad * 4 + reg] = p;
        }
    }
    __syncthreads();
    if (tid < 128) {
        float s = 0.f;
        #pragma unroll
        for (int i = 0; i < 8; ++i) s += e_part[i][tid];
        e_ws[m0 + tid] = s;
    }
}

// K4: softmax (recomputed per block, shift-invariant so b_g dropped) + ctx chunk.
// grid (32 b, 8 chunks of 128 cols), 512 thr = 8 waves x 200 t each. No atomics.
__global__ void ctx_softmax_kernel(const float* __restrict__ enc,
                                   const float* __restrict__ e_ws,
                                   const int* __restrict__ lens,
                                   float* __restrict__ w_out,
                                   float* __restrict__ ctx) {
    int b = blockIdx.x, ch = blockIdx.y;
    int tid = threadIdx.x;
    __shared__ float w_sm[1600];
    __shared__ float red[512];
    __shared__ float part[8][128];
    int len = lens[b];
    const float* e = e_ws + b * TT;
    float mx = -3.4e38f;
    for (int t = tid; t < len; t += 512) mx = fmaxf(mx, e[t]);
    red[tid] = mx; __syncthreads();
    for (int s = 256; s > 0; s >>= 1) {
        if (tid < s) red[tid] = fmaxf(red[tid], red[tid + s]);
        __syncthreads();
    }
    mx = red[0]; __syncthreads();
    float sum = 0.f;
    for (int t = tid; t < TT; t += 512) {
        float p = (t < len) ? expf(2.f * (e[t] - mx)) : 0.f;
        w_sm[t] = p; sum += p;
    }
    red[tid] = sum; __syncthreads();
    for (int s = 256; s > 0; s >>= 1) {
        if (tid < s) red[tid] += red[tid + s];
        __syncthreads();
    }
    float inv = 1.f / red[0];
    __syncthreads();
    for (int t = tid; t < TT; t += 512) {
        float wv = w_sm[t] * inv;
        w_sm[t] = wv;
        if (ch == 0) w_out[b * TT + t] = wv;
    }
    __syncthreads();
    // ctx: wave w8 covers t in [w8*200, w8*200+200), lanes cover 128 cols as float2
    int lane2 = tid & 63, w8 = tid >> 6;
    int tb = w8 * 200;
    const float* base = enc + (size_t)(b * TT + tb) * EE + ch * 128 + lane2 * 2;
    float cx = 0.f, cy = 0.f;
    #pragma unroll 1
    for (int i = 0; i < 200; i += 8) {
        #pragma unroll
        for (int j = 0; j < 8; ++j) {
            float2 v = *reinterpret_cast<const float2*>(base + (size_t)(i + j) * EE);
            float ww = w_sm[tb + i + j];
            cx += ww * v.x; cy += ww * v.y;
        }
    }
    part[w8][lane2 * 2] = cx;
    part[w8][lane2 * 2 + 1] = cy;
    __syncthreads();
    if (tid < 128) {
        float s = 0.f;
        #pragma unroll
        for (int i = 0; i < 8; ++i) s += part[i][tid];
        ctx[b * EE + ch * 128 + tid] = s;
    }
}

extern "C" void kernel_launch(void* const* d_in, const int* in_sizes, int n_in,
                              void* d_out, int out_size, void* d_ws, size_t ws_size,
                              hipStream_t stream) {
    const float* enc      = (const float*)d_in[0];
    const int*   lens     = (const int*)d_in[1];
    const float* dec_z    = (const float*)d_in[2];
    const float* att_prev = (const float*)d_in[3];
    const float* att_h    = (const float*)d_in[4];
    const float* att_c    = (const float*)d_in[5];
    const float* W_enc    = (const float*)d_in[6];
    const float* b_enc    = (const float*)d_in[7];
    const float* W_dec    = (const float*)d_in[8];
    const float* conv_w   = (const float*)d_in[9];
    const float* W_ih     = (const float*)d_in[10];
    const float* W_hh     = (const float*)d_in[11];
    const float* W_g      = (const float*)d_in[12];

    float* out = (float*)d_out;
    float* ws  = (float*)d_ws;
    float* af   = ws + AF_OFF;
    float* r_ws = ws + R_OFF;
    float* e_ws = ws + E_OFF;
    unsigned short* Wbf = (unsigned short*)(ws + WBF_OFF);

    prep_kernel<<<832, 256, 0, stream>>>(att_prev, conv_w, W_enc, af, Wbf);
    gates_lstm_kernel<<<256, 512, 0, stream>>>(af, att_h, dec_z, att_c,
                                               W_ih, W_hh, W_dec, out, r_ws);
    score_gemm_kernel<<<400, 1024, 0, stream>>>(enc, Wbf, b_enc, r_ws, W_g, e_ws);
    ctx_softmax_kernel<<<dim3(BB, 8), 512, 0, stream>>>(enc, e_ws, lens,
                                                        out + W_OFF, out + CTX_OFF);
}